// Round 1
// baseline (212.958 us; speedup 1.0000x reference)
//
#include <hip/hip_runtime.h>
#include <hip/hip_bf16.h>

// Problem constants (N=4, L=4096, E=1024, H=16, D=64)
#define L_SEQ 4096
#define EMB   1024

// ---------------------------------------------------------------------------
// K1: Wvsum[d][e] = sum_{h=0..15} Wv[h*64+d][e]      (64 x 1024 output)
// ---------------------------------------------------------------------------
__global__ void k_wvsum(const float* __restrict__ Wv, float* __restrict__ Wvsum) {
    int g = blockIdx.x * blockDim.x + threadIdx.x;   // 0..65535
    int d = g >> 10;
    int e = g & 1023;
    float s = 0.f;
#pragma unroll
    for (int h = 0; h < 16; ++h)
        s += Wv[(h * 64 + d) * 1024 + e];
    Wvsum[g] = s;                                     // row-major [d][e]
}

// ---------------------------------------------------------------------------
// K2: vsum[row][c] = sum_e x[row][e] * Wvsum[c][e]
//     rows = 16384 (N*L), c = 0..63.  Tile: 32 rows x 64 cols, 256 threads,
//     thread-tile 2x4, float4 along K.
// ---------------------------------------------------------------------------
__global__ __launch_bounds__(256) void k_vsum(const float* __restrict__ x,
                                              const float* __restrict__ Wvsum,
                                              float* __restrict__ vsum) {
    __shared__ float4 As[16][33];   // [e4][row]  (pad: 33 mod 8 == 1 -> conflict-free)
    __shared__ float4 Bs[16][65];   // [e4][col]

    const int t  = threadIdx.x;
    const int c0 = t & 15;          // col group; thread cols = c0 + 16j
    const int r0 = t >> 4;          // 0..15;     thread rows = r0 + 16i
    const int R0 = blockIdx.x * 32;

    float acc[2][4] = {{0.f,0.f,0.f,0.f},{0.f,0.f,0.f,0.f}};

    for (int e0 = 0; e0 < 1024; e0 += 64) {
        // stage A: 32 rows x 16 float4-cells
#pragma unroll
        for (int u = 0; u < 2; ++u)
            As[c0][r0 + 16*u] = *reinterpret_cast<const float4*>(
                &x[(size_t)(R0 + r0 + 16*u) * 1024 + e0 + c0 * 4]);
        // stage B: 64 cols x 16 cells
#pragma unroll
        for (int u = 0; u < 4; ++u)
            Bs[c0][r0 + 16*u] = *reinterpret_cast<const float4*>(
                &Wvsum[(r0 + 16*u) * 1024 + e0 + c0 * 4]);
        __syncthreads();

#pragma unroll
        for (int kk = 0; kk < 16; ++kk) {
            float4 a0 = As[kk][r0];
            float4 a1 = As[kk][r0 + 16];
            float4 b[4];
#pragma unroll
            for (int j = 0; j < 4; ++j) b[j] = Bs[kk][c0 + 16*j];
#pragma unroll
            for (int j = 0; j < 4; ++j) {
                acc[0][j] = fmaf(a0.x, b[j].x, acc[0][j]);
                acc[0][j] = fmaf(a0.y, b[j].y, acc[0][j]);
                acc[0][j] = fmaf(a0.z, b[j].z, acc[0][j]);
                acc[0][j] = fmaf(a0.w, b[j].w, acc[0][j]);
                acc[1][j] = fmaf(a1.x, b[j].x, acc[1][j]);
                acc[1][j] = fmaf(a1.y, b[j].y, acc[1][j]);
                acc[1][j] = fmaf(a1.z, b[j].z, acc[1][j]);
                acc[1][j] = fmaf(a1.w, b[j].w, acc[1][j]);
            }
        }
        __syncthreads();
    }

#pragma unroll
    for (int i = 0; i < 2; ++i)
#pragma unroll
        for (int j = 0; j < 4; ++j)
            vsum[(size_t)(R0 + r0 + 16*i) * 64 + c0 + 16*j] = acc[i][j];
}

// ---------------------------------------------------------------------------
// K3: U[zr][f] = sum_e Z[zr][e] * Wo[f][e] + bo[f],  Z = vsum viewed (1024x1024)
//     then broadcast: out[n*4096*1024 + (q*256+m)*1024 + f] = U[n*256+m][f], q=0..15
//     Tile: 32 zr-rows x 64 f-cols, 256 threads, thread-tile 2x4.
// ---------------------------------------------------------------------------
__global__ __launch_bounds__(256) void k_out(const float* __restrict__ Z,
                                             const float* __restrict__ Wo,
                                             const float* __restrict__ bo,
                                             float* __restrict__ out) {
    __shared__ float4 As[16][33];
    __shared__ float4 Bs[16][65];

    const int t  = threadIdx.x;
    const int c0 = t & 15;
    const int r0 = t >> 4;
    const int rt = blockIdx.x & 31;   // 32 row tiles (1024/32)
    const int ct = blockIdx.x >> 5;   // 16 col tiles (1024/64)
    const int ZR0 = rt * 32;
    const int F0  = ct * 64;

    float acc[2][4] = {{0.f,0.f,0.f,0.f},{0.f,0.f,0.f,0.f}};

    for (int e0 = 0; e0 < 1024; e0 += 64) {
#pragma unroll
        for (int u = 0; u < 2; ++u)
            As[c0][r0 + 16*u] = *reinterpret_cast<const float4*>(
                &Z[(size_t)(ZR0 + r0 + 16*u) * 1024 + e0 + c0 * 4]);
#pragma unroll
        for (int u = 0; u < 4; ++u)
            Bs[c0][r0 + 16*u] = *reinterpret_cast<const float4*>(
                &Wo[(size_t)(F0 + r0 + 16*u) * 1024 + e0 + c0 * 4]);
        __syncthreads();

#pragma unroll
        for (int kk = 0; kk < 16; ++kk) {
            float4 a0 = As[kk][r0];
            float4 a1 = As[kk][r0 + 16];
            float4 b[4];
#pragma unroll
            for (int j = 0; j < 4; ++j) b[j] = Bs[kk][c0 + 16*j];
#pragma unroll
            for (int j = 0; j < 4; ++j) {
                acc[0][j] = fmaf(a0.x, b[j].x, acc[0][j]);
                acc[0][j] = fmaf(a0.y, b[j].y, acc[0][j]);
                acc[0][j] = fmaf(a0.z, b[j].z, acc[0][j]);
                acc[0][j] = fmaf(a0.w, b[j].w, acc[0][j]);
                acc[1][j] = fmaf(a1.x, b[j].x, acc[1][j]);
                acc[1][j] = fmaf(a1.y, b[j].y, acc[1][j]);
                acc[1][j] = fmaf(a1.z, b[j].z, acc[1][j]);
                acc[1][j] = fmaf(a1.w, b[j].w, acc[1][j]);
            }
        }
        __syncthreads();
    }

    // epilogue: add bias, write each U element to its 16 broadcast locations
#pragma unroll
    for (int i = 0; i < 2; ++i) {
        const int zr = ZR0 + r0 + 16*i;
        const int n  = zr >> 8;           // batch
        const int m  = zr & 255;          // l' mod 256
        const size_t base_n = (size_t)n * L_SEQ * EMB;
#pragma unroll
        for (int j = 0; j < 4; ++j) {
            const int f = F0 + c0 + 16*j;
            const float val = acc[i][j] + bo[f];
#pragma unroll
            for (int q = 0; q < 16; ++q)
                out[base_n + (size_t)(q * 256 + m) * EMB + f] = val;
        }
    }
}

// ---------------------------------------------------------------------------
extern "C" void kernel_launch(void* const* d_in, const int* in_sizes, int n_in,
                              void* d_out, int out_size, void* d_ws, size_t ws_size,
                              hipStream_t stream) {
    const float* x  = (const float*)d_in[0];
    // d_in[1] = Wq, d_in[2] = Wk  — provably unused (softmax row-sums == 1)
    const float* Wv = (const float*)d_in[3];
    const float* Wo = (const float*)d_in[4];
    const float* bo = (const float*)d_in[5];
    float* out = (float*)d_out;

    // workspace layout: Wvsum (64*1024 floats = 256 KB) | vsum (16384*64 floats = 4 MB)
    float* Wvsum = (float*)d_ws;
    float* vsum  = Wvsum + 64 * 1024;

    k_wvsum<<<256, 256, 0, stream>>>(Wv, Wvsum);
    k_vsum <<<512, 256, 0, stream>>>(x, Wvsum, vsum);
    k_out  <<<512, 256, 0, stream>>>(vsum, Wo, bo, out);
}

// Round 2
// 189.537 us; speedup vs baseline: 1.1236x; 1.1236x over previous
//
#include <hip/hip_runtime.h>
#include <hip/hip_bf16.h>

// Problem: N=4, L=4096, E=1024, H=16, D=64.
// Algebra (verified passing in round 1): softmax row-sums==1 collapse the op to
//   Z (1024x1024, = x @ WvsumT reshaped) ; U = Z @ Wo^T + bo ; out = 16x broadcast of U.
// This round: both GEMMs via bf16 MFMA with hi/lo split (fp32-grade accuracy).

typedef unsigned short u16;
typedef __attribute__((ext_vector_type(8))) short  short8v;  // 8 bf16 (4 VGPR)
typedef __attribute__((ext_vector_type(4))) float  f32x4;
typedef __attribute__((ext_vector_type(4))) u16    ushort4v;

__device__ __forceinline__ u16 f2bf(float f) {
    unsigned u = __float_as_uint(f);
    u += 0x7fffu + ((u >> 16) & 1u);          // round-to-nearest-even
    return (u16)(u >> 16);
}
__device__ __forceinline__ float bf2f(u16 h) {
    return __uint_as_float(((unsigned)h) << 16);
}
__device__ __forceinline__ f32x4 mfma16(short8v a, short8v b, f32x4 c) {
    return __builtin_amdgcn_mfma_f32_16x16x32_bf16(a, b, c, 0, 0, 0);
}

// ---------------------------------------------------------------------------
// K1: Bpk[e8*64 + c] = short8{ Wvsum[c][e8*8 .. e8*8+7] } split hi/lo,
//     where Wvsum[c][e] = sum_h Wv[h*64+c][e].  Fragment-packed for MFMA B.
// ---------------------------------------------------------------------------
__global__ __launch_bounds__(256) void k_pack_b(const float* __restrict__ Wv,
                                                u16* __restrict__ Bh,
                                                u16* __restrict__ Bl) {
    int t  = blockIdx.x * 256 + threadIdx.x;   // 8192 threads
    int c  = t >> 7;                           // 0..63
    int e8 = t & 127;                          // 0..127
    int e  = e8 << 3;
    float ss[8] = {0.f,0.f,0.f,0.f,0.f,0.f,0.f,0.f};
#pragma unroll
    for (int h = 0; h < 16; ++h) {
        const f32x4* p = (const f32x4*)&Wv[(size_t)((h << 6) + c) * 1024 + e];
        f32x4 a = p[0], b = p[1];
        ss[0]+=a[0]; ss[1]+=a[1]; ss[2]+=a[2]; ss[3]+=a[3];
        ss[4]+=b[0]; ss[5]+=b[1]; ss[6]+=b[2]; ss[7]+=b[3];
    }
    short8v h8, l8;
#pragma unroll
    for (int j = 0; j < 8; ++j) {
        u16 hh = f2bf(ss[j]);
        h8[j] = (short)hh;
        l8[j] = (short)f2bf(ss[j] - bf2f(hh));
    }
    ((short8v*)Bh)[e8 * 64 + c] = h8;
    ((short8v*)Bl)[e8 * 64 + c] = l8;
}

// ---------------------------------------------------------------------------
// K2: Z[zr][e] (fp32, 1024x1024 view) = vsum = x @ WvsumT via MFMA.
//     Block: 32 rows x 64 cols, 4 waves (wave = 16 cols x 32 rows), BK=128.
// ---------------------------------------------------------------------------
__global__ __launch_bounds__(256) void k_vsum_mfma(const float* __restrict__ x,
                                                   const u16* __restrict__ Bh,
                                                   const u16* __restrict__ Bl,
                                                   float* __restrict__ Z) {
    __shared__ __align__(16) u16 Ah[32][136];   // pad: 272B row stride -> conflict-free b128
    __shared__ __align__(16) u16 Al[32][136];

    const int t    = threadIdx.x;
    const int lane = t & 63;
    const int w    = t >> 6;            // 0..3
    const int l15  = lane & 15;
    const int lh   = lane >> 4;         // 0..3
    const int cb   = w << 4;            // wave's 16 cols
    const int R0   = blockIdx.x << 5;   // 32 rows per block

    const int sr = t >> 3;              // staging row 0..31
    const int se = (t & 7) << 4;        // staging e-base

    const short8v* bh8 = (const short8v*)Bh;
    const short8v* bl8 = (const short8v*)Bl;

    f32x4 acc0 = {0.f,0.f,0.f,0.f};
    f32x4 acc1 = {0.f,0.f,0.f,0.f};

    for (int ch = 0; ch < 8; ++ch) {
        const int e0 = ch << 7;
        // stage A (x) tile 32x128 as bf16 hi/lo
#pragma unroll
        for (int q = 0; q < 4; ++q) {
            f32x4 v = *(const f32x4*)&x[(size_t)(R0 + sr) * 1024 + e0 + se + (q << 2)];
            ushort4v h4, l4;
#pragma unroll
            for (int j = 0; j < 4; ++j) {
                u16 hh = f2bf(v[j]);
                h4[j] = hh;
                l4[j] = f2bf(v[j] - bf2f(hh));
            }
            *(ushort4v*)&Ah[sr][se + (q << 2)] = h4;
            *(ushort4v*)&Al[sr][se + (q << 2)] = l4;
        }
        __syncthreads();
#pragma unroll
        for (int ktl = 0; ktl < 4; ++ktl) {
            const int koff = (ktl << 5) + (lh << 3);
            short8v ah0 = *(const short8v*)&Ah[l15][koff];
            short8v al0 = *(const short8v*)&Al[l15][koff];
            short8v ah1 = *(const short8v*)&Ah[16 + l15][koff];
            short8v al1 = *(const short8v*)&Al[16 + l15][koff];
            const int ktg  = (ch << 2) + ktl;
            const int bidx = ((ktg << 2) + lh) * 64 + cb + l15;
            short8v bhf = bh8[bidx];
            short8v blf = bl8[bidx];
            acc0 = mfma16(ah0, bhf, acc0);
            acc0 = mfma16(ah0, blf, acc0);
            acc0 = mfma16(al0, bhf, acc0);
            acc1 = mfma16(ah1, bhf, acc1);
            acc1 = mfma16(ah1, blf, acc1);
            acc1 = mfma16(al1, bhf, acc1);
        }
        __syncthreads();
    }
    // epilogue: vsum row vr = R0 + rf*16 + lh*4 + reg -> Z[zr][(vr&15)*64 + c]
    const int zrbase = blockIdx.x << 1;
#pragma unroll
    for (int reg = 0; reg < 4; ++reg) {
        int v15 = (lh << 2) + reg;
        Z[(size_t)zrbase       * 1024 + v15 * 64 + cb + l15] = acc0[reg];
        Z[(size_t)(zrbase + 1) * 1024 + v15 * 64 + cb + l15] = acc1[reg];
    }
}

// ---------------------------------------------------------------------------
// K3: U = Z @ Wo^T + bo (MFMA, Z split on the fly, Wo cvt on the fly),
//     fused 16x broadcast epilogue with float4 non-temporal streaming stores.
//     Block: 64 zr-rows x 64 f-cols; wave = 16 cols x 64 rows; BK=128.
// ---------------------------------------------------------------------------
__global__ __launch_bounds__(256) void k_out_mfma(const float* __restrict__ Z,
                                                  const float* __restrict__ Wo,
                                                  const float* __restrict__ bo,
                                                  float* __restrict__ out) {
    __shared__ __align__(16) unsigned char smem[2 * 64 * 136 * 2];
    u16 (*Zh)[136] = (u16(*)[136])smem;
    u16 (*Zl)[136] = (u16(*)[136])(smem + 64 * 136 * 2);

    const int t    = threadIdx.x;
    const int lane = t & 63;
    const int w    = t >> 6;
    const int l15  = lane & 15;
    const int lh   = lane >> 4;
    const int zr0  = (blockIdx.x & 15) << 6;   // 64 U-rows
    const int f0   = (blockIdx.x >> 4) << 6;   // 64 f-cols
    const int fb   = f0 + (w << 4);            // wave's col base

    const int sr = t >> 4;          // 0..15
    const int se = (t & 15) << 3;   // 8 floats

    const f32x4* wrow = (const f32x4*)&Wo[(size_t)(fb + l15) * 1024];

    f32x4 acc0 = {0.f,0.f,0.f,0.f};
    f32x4 acc1 = {0.f,0.f,0.f,0.f};
    f32x4 acc2 = {0.f,0.f,0.f,0.f};
    f32x4 acc3 = {0.f,0.f,0.f,0.f};

    for (int ch = 0; ch < 8; ++ch) {
        const int e0 = ch << 7;
        // stage Z tile 64x128 as bf16 hi/lo
#pragma unroll
        for (int p = 0; p < 4; ++p) {
            int r = (p << 4) + sr;
#pragma unroll
            for (int qq = 0; qq < 2; ++qq) {
                f32x4 v = *(const f32x4*)&Z[(size_t)(zr0 + r) * 1024 + e0 + se + (qq << 2)];
                ushort4v h4, l4;
#pragma unroll
                for (int j = 0; j < 4; ++j) {
                    u16 hh = f2bf(v[j]);
                    h4[j] = hh;
                    l4[j] = f2bf(v[j] - bf2f(hh));
                }
                *(ushort4v*)&Zh[r][se + (qq << 2)] = h4;
                *(ushort4v*)&Zl[r][se + (qq << 2)] = l4;
            }
        }
        __syncthreads();
#pragma unroll
        for (int ktl = 0; ktl < 4; ++ktl) {
            const int koff = (ktl << 5) + (lh << 3);
            const int widx = (e0 + koff) >> 2;
            f32x4 w0 = wrow[widx], w1 = wrow[widx + 1];
            short8v bhf, blf;
            {
                float wf[8] = {w0[0], w0[1], w0[2], w0[3], w1[0], w1[1], w1[2], w1[3]};
#pragma unroll
                for (int j = 0; j < 8; ++j) {
                    u16 hh = f2bf(wf[j]);
                    bhf[j] = (short)hh;
                    blf[j] = (short)f2bf(wf[j] - bf2f(hh));
                }
            }
            short8v ah, al;
            ah = *(const short8v*)&Zh[l15][koff];
            al = *(const short8v*)&Zl[l15][koff];
            acc0 = mfma16(ah, bhf, acc0); acc0 = mfma16(ah, blf, acc0); acc0 = mfma16(al, bhf, acc0);
            ah = *(const short8v*)&Zh[16 + l15][koff];
            al = *(const short8v*)&Zl[16 + l15][koff];
            acc1 = mfma16(ah, bhf, acc1); acc1 = mfma16(ah, blf, acc1); acc1 = mfma16(al, bhf, acc1);
            ah = *(const short8v*)&Zh[32 + l15][koff];
            al = *(const short8v*)&Zl[32 + l15][koff];
            acc2 = mfma16(ah, bhf, acc2); acc2 = mfma16(ah, blf, acc2); acc2 = mfma16(al, bhf, acc2);
            ah = *(const short8v*)&Zh[48 + l15][koff];
            al = *(const short8v*)&Zl[48 + l15][koff];
            acc3 = mfma16(ah, bhf, acc3); acc3 = mfma16(ah, blf, acc3); acc3 = mfma16(al, bhf, acc3);
        }
        __syncthreads();
    }

    // ---- epilogue: U tile -> LDS (reusing Zh/Zl space), then 16x broadcast ----
    float (*Ut)[68] = (float(*)[68])smem;       // 64x68 fp32 = 17408 B (fits in Zh)
    const float bov = bo[fb + l15];
#pragma unroll
    for (int reg = 0; reg < 4; ++reg) {
        int rl = (lh << 2) + reg;
        int cl = (w << 4) + l15;
        Ut[rl     ][cl] = acc0[reg] + bov;
        Ut[16 + rl][cl] = acc1[reg] + bov;
        Ut[32 + rl][cl] = acc2[reg] + bov;
        Ut[48 + rl][cl] = acc3[reg] + bov;
    }
    __syncthreads();

    const int fq = t & 15, rr = t >> 4;
#pragma unroll
    for (int p = 0; p < 4; ++p) {
        int r = (p << 4) + rr;
        f32x4 val = *(const f32x4*)&Ut[r][fq << 2];
        int zr = zr0 + r;
        float* ob = out + ((size_t)(zr >> 8) << 22) + ((size_t)(zr & 255) << 10)
                        + f0 + (fq << 2);
#pragma unroll
        for (int q = 0; q < 16; ++q)
            __builtin_nontemporal_store(val, (f32x4*)(ob + ((size_t)q << 18)));
    }
}

// ---------------------------------------------------------------------------
extern "C" void kernel_launch(void* const* d_in, const int* in_sizes, int n_in,
                              void* d_out, int out_size, void* d_ws, size_t ws_size,
                              hipStream_t stream) {
    const float* x  = (const float*)d_in[0];
    // d_in[1]=Wq, d_in[2]=Wk unused (softmax row-sums == 1)
    const float* Wv = (const float*)d_in[3];
    const float* Wo = (const float*)d_in[4];
    const float* bo = (const float*)d_in[5];
    float* out = (float*)d_out;

    // ws: Bpk_hi (128 KB) | Bpk_lo (128 KB) | Z fp32 (4 MB)  = 4.25 MB (proven size)
    u16*   Bh = (u16*)d_ws;
    u16*   Bl = Bh + 64 * 1024;
    float* Z  = (float*)(Bl + 64 * 1024);

    k_pack_b   <<<32,  256, 0, stream>>>(Wv, Bh, Bl);
    k_vsum_mfma<<<512, 256, 0, stream>>>(x, Bh, Bl, Z);
    k_out_mfma <<<256, 256, 0, stream>>>(Z, Wo, bo, out);
}